// Round 10
// baseline (4355.951 us; speedup 1.0000x reference)
//
#include <hip/hip_runtime.h>

typedef unsigned char u8;
typedef unsigned int u32;

#define T_STEPS 4
#define B_SZ 8
#define C_IN 512
#define CH 2048
#define N_SP 1024
#define S_C ((size_t)B_SZ * C_IN * N_SP)    // elems per timestep

// ---------------------------------------------------------------------------
// lif_x: x [T,B,C,N] fp32 -> xs u8 spikes, same flat layout (round-2 verbatim).
// ---------------------------------------------------------------------------
__global__ __launch_bounds__(256) void lif_x_kernel(const float* __restrict__ in,
                                                    u8* __restrict__ out)
{
    size_t i = (size_t)blockIdx.x * 256 + threadIdx.x;
    float v = 0.0f;
    #pragma unroll
    for (int t = 0; t < T_STEPS; ++t) {
        float x = in[(size_t)t * S_C + i];
        v += (x - v) * 0.5f;
        u8 s = (v >= 0.5f) ? 1 : 0;
        out[(size_t)t * S_C + i] = s;
        v = s ? 0.0f : v;
    }
}

// ---------------------------------------------------------------------------
// Fused GEMM + BN (+bias) + LIF, fp32. Per-output math is ascending-k with a
// single fp32 accumulator -> bit-identical to rounds 2/6/7/8/9.
// Layouts: X [TB][K][N], W [CO][K] fp32, Y [TB][CO][N].
// MODE 0: LIF -> u8 spikes. MODE 1: y + res -> f32. MODE 2: LIF spike + in-place res -> f32.
// BSRC 0: u8 X. BSRC 1: u8 X * kvsf[k] at staging (proj mask). BSRC 2: f32 X (fc1).
// Tile 64co x 128n, 256 threads, per-thread 4co x 8n.
// DOUBLE-BUFFERED LDS, ONE barrier per k-tile:
//   prefetch(next)->regs ; compute(buf p) ; stage regs->buf p^1 ; barrier ; flip.
// Writes to p^1 are safe pre-barrier (its readers finished at previous barrier).
// NOTE: no min-waves hint (round 8: (256,4) clamps to 64 VGPR and spills).
// ---------------------------------------------------------------------------
template<int MODE, int BSRC, bool BIAS, int K, int CO, int NSEL>
__global__ __launch_bounds__(256) void mm(
    const float* __restrict__ W0, const float* __restrict__ W1, const float* __restrict__ W2,
    const void* __restrict__ Xv,
    const float* __restrict__ bn0, const float* __restrict__ bn1, const float* __restrict__ bn2,
    const float* __restrict__ bias,
    const float* __restrict__ kvsf,
    const float* __restrict__ res,
    void* Y0, void* Y1, void* Y2)
{
    constexpr int BM = 64;
    constexpr int NB_CO = CO / BM;
    constexpr int KT = K / 16;

    __shared__ float As[2][16][76];   // [buf][k][co]  stride 76: 16B-aligned, <=2-way
    __shared__ float Xs[2][16][136];  // [buf][k][n]

    const int bid = blockIdx.x;
    const int nblk = bid & 7;         // XCD-pinned n-slice
    int slot = bid >> 3;
    const int cb = slot % NB_CO; slot /= NB_CO;
    const int sel = (NSEL > 1) ? (slot % NSEL) : 0;
    const int b   = (NSEL > 1) ? (slot / NSEL) : slot;

    const float* W   = (NSEL == 1 || sel == 0) ? W0  : (sel == 1 ? W1  : W2);
    const float* bnp = (NSEL == 1 || sel == 0) ? bn0 : (sel == 1 ? bn1 : bn2);
    void* Yv         = (NSEL == 1 || sel == 0) ? Y0  : (sel == 1 ? Y1  : Y2);

    const int coBase = cb * BM;
    const int n0blk = nblk * 128;
    const int tid = threadIdx.x;
    const int tx = tid & 15, ty = tid >> 4;

    // staging indices: W rows by tid>>2, X row = ty, X cols = tx*4 / tx*4+64
    const int wr = tid >> 2;
    const int wk4 = (tid & 3) * 4;

    // BN constants (round-2 expressions)
    float scale[4], shift[4];
    #pragma unroll
    for (int i = 0; i < 4; ++i) {
        const int co = coBase + ty * 4 + i;
        const float g = bnp[co], be = bnp[CO + co];
        const float mn = bnp[2 * CO + co], vr = bnp[3 * CO + co];
        scale[i] = g / sqrtf(vr + 1e-5f);
        shift[i] = be - mn * scale[i];
        if (BIAS) shift[i] += bias[co] * scale[i];
    }

    float vst[4][8];
    if (MODE != 1) {
        #pragma unroll
        for (int i = 0; i < 4; ++i)
            #pragma unroll
            for (int j = 0; j < 8; ++j) vst[i][j] = 0.0f;
    }

    float4 wreg;
    u32 xa, xb;
    float mreg = 1.0f;
    float4 xfa, xfb;

    auto prefetch = [&](int tbq, int kt) {
        wreg = *reinterpret_cast<const float4*>(
            W + (size_t)(coBase + wr) * K + kt * 16 + wk4);
        if constexpr (BSRC <= 1) {
            const u8* xp = (const u8*)Xv + (size_t)tbq * K * N_SP
                           + (size_t)(kt * 16 + ty) * N_SP + n0blk + tx * 4;
            xa = *reinterpret_cast<const u32*>(xp);
            xb = *reinterpret_cast<const u32*>(xp + 64);
            if constexpr (BSRC == 1)
                mreg = kvsf[(size_t)tbq * K + kt * 16 + ty];
        } else {
            const float* xp = (const float*)Xv + (size_t)tbq * K * N_SP
                              + (size_t)(kt * 16 + ty) * N_SP + n0blk + tx * 4;
            xfa = *reinterpret_cast<const float4*>(xp);
            xfb = *reinterpret_cast<const float4*>(xp + 64);
        }
    };

    auto stage = [&](int pp) {
        As[pp][wk4 + 0][wr] = wreg.x;
        As[pp][wk4 + 1][wr] = wreg.y;
        As[pp][wk4 + 2][wr] = wreg.z;
        As[pp][wk4 + 3][wr] = wreg.w;
        if constexpr (BSRC <= 1) {
            float4 s0, s1;
            s0.x = (float)( xa        & 0xFFu);
            s0.y = (float)((xa >> 8 ) & 0xFFu);
            s0.z = (float)((xa >> 16) & 0xFFu);
            s0.w = (float)( xa >> 24        );
            s1.x = (float)( xb        & 0xFFu);
            s1.y = (float)((xb >> 8 ) & 0xFFu);
            s1.z = (float)((xb >> 16) & 0xFFu);
            s1.w = (float)( xb >> 24        );
            if constexpr (BSRC == 1) {
                s0.x *= mreg; s0.y *= mreg; s0.z *= mreg; s0.w *= mreg;   // 0/1 x 0/1: exact
                s1.x *= mreg; s1.y *= mreg; s1.z *= mreg; s1.w *= mreg;
            }
            *reinterpret_cast<float4*>(&Xs[pp][ty][tx * 4]) = s0;
            *reinterpret_cast<float4*>(&Xs[pp][ty][tx * 4 + 64]) = s1;
        } else {
            *reinterpret_cast<float4*>(&Xs[pp][ty][tx * 4]) = xfa;
            *reinterpret_cast<float4*>(&Xs[pp][ty][tx * 4 + 64]) = xfb;
        }
    };

    int p = 0;
    prefetch(b, 0);       // (t=0, kt=0)
    stage(0);
    __syncthreads();

    for (int t = 0; t < T_STEPS; ++t) {
        const int tb = t * B_SZ + b;

        float acc[4][8];
        #pragma unroll
        for (int i = 0; i < 4; ++i)
            #pragma unroll
            for (int j = 0; j < 8; ++j) acc[i][j] = 0.0f;

        for (int kt = 0; kt < KT; ++kt) {
            const bool last = (kt == KT - 1) && (t == T_STEPS - 1);
            if (!last) {
                const int nkt = (kt + 1 < KT) ? kt + 1 : 0;
                const int ntb = (kt + 1 < KT) ? tb : tb + B_SZ;
                prefetch(ntb, nkt);
            }
            #pragma unroll
            for (int kk = 0; kk < 16; ++kk) {
                float4 av = *reinterpret_cast<const float4*>(&As[p][kk][ty * 4]);
                float4 x0 = *reinterpret_cast<const float4*>(&Xs[p][kk][tx * 4]);
                float4 x1 = *reinterpret_cast<const float4*>(&Xs[p][kk][tx * 4 + 64]);
                float wa[4] = {av.x, av.y, av.z, av.w};
                float xw[8] = {x0.x, x0.y, x0.z, x0.w, x1.x, x1.y, x1.z, x1.w};
                #pragma unroll
                for (int i = 0; i < 4; ++i)
                    #pragma unroll
                    for (int j = 0; j < 8; ++j)
                        acc[i][j] += wa[i] * xw[j];   // ascending-k, single acc
            }
            if (!last) {
                stage(p ^ 1);
                __syncthreads();
                p ^= 1;
            }
        }

        // epilogue for this timestep (round-2 expressions, bit-identical).
        // n positions: base (tx*4 + j) and base+64 (j = 4..7).
        #pragma unroll
        for (int i = 0; i < 4; ++i) {
            const int co = coBase + ty * 4 + i;
            const size_t base = ((size_t)tb * CO + co) * N_SP + n0blk + tx * 4;
            if constexpr (MODE == 0) {
                u32 p0 = 0, p1 = 0;
                #pragma unroll
                for (int j = 0; j < 8; ++j) {
                    const float y = acc[i][j] * scale[i] + shift[i];
                    float v = vst[i][j];
                    v += (y - v) * 0.5f;
                    const u32 s = (v >= 0.5f) ? 1u : 0u;
                    vst[i][j] = s ? 0.0f : v;
                    if (j < 4) p0 |= s << (8 * j); else p1 |= s << (8 * (j - 4));
                }
                *reinterpret_cast<u32*>((u8*)Yv + base) = p0;
                *reinterpret_cast<u32*>((u8*)Yv + base + 64) = p1;
            } else if constexpr (MODE == 1) {
                float4 r0 = *reinterpret_cast<const float4*>(res + base);
                float4 r1 = *reinterpret_cast<const float4*>(res + base + 64);
                float rr[8] = {r0.x, r0.y, r0.z, r0.w, r1.x, r1.y, r1.z, r1.w};
                float o[8];
                #pragma unroll
                for (int j = 0; j < 8; ++j)
                    o[j] = acc[i][j] * scale[i] + shift[i] + rr[j];
                float4 s0 = {o[0], o[1], o[2], o[3]};
                float4 s1 = {o[4], o[5], o[6], o[7]};
                *reinterpret_cast<float4*>((float*)Yv + base) = s0;
                *reinterpret_cast<float4*>((float*)Yv + base + 64) = s1;
            } else {
                float* op = (float*)Yv + base;
                float4 r0 = *reinterpret_cast<const float4*>(op);
                float4 r1 = *reinterpret_cast<const float4*>(op + 64);
                float rr[8] = {r0.x, r0.y, r0.z, r0.w, r1.x, r1.y, r1.z, r1.w};
                float o[8];
                #pragma unroll
                for (int j = 0; j < 8; ++j) {
                    const float y = acc[i][j] * scale[i] + shift[i];
                    float v = vst[i][j];
                    v += (y - v) * 0.5f;
                    const u32 s = (v >= 0.5f) ? 1u : 0u;
                    vst[i][j] = s ? 0.0f : v;
                    o[j] = rr[j] + (s ? 1.0f : 0.0f);
                }
                float4 s0 = {o[0], o[1], o[2], o[3]};
                float4 s1 = {o[4], o[5], o[6], o[7]};
                *reinterpret_cast<float4*>(op) = s0;
                *reinterpret_cast<float4*>(op + 64) = s1;
            }
        }
    }
}

// ---------------------------------------------------------------------------
// kv_raw[row=tb*C+c] = sum_n k*v  (exact integer; round-2 verbatim)
// ---------------------------------------------------------------------------
__global__ __launch_bounds__(256) void kv_reduce(const u8* __restrict__ ks,
                                                 const u8* __restrict__ vs,
                                                 float* __restrict__ kv)
{
    const int row = blockIdx.x * 4 + (threadIdx.x >> 6);  // [0, T*B*C)
    const int lane = threadIdx.x & 63;
    const u8* kp = ks + (size_t)row * N_SP;
    const u8* vp = vs + (size_t)row * N_SP;
    int acc = 0;
    #pragma unroll
    for (int n = 0; n < N_SP; n += 256) {
        uchar4 a = *reinterpret_cast<const uchar4*>(kp + n + lane * 4);
        uchar4 c = *reinterpret_cast<const uchar4*>(vp + n + lane * 4);
        acc += (a.x & c.x) + (a.y & c.y) + (a.z & c.z) + (a.w & c.w);
    }
    #pragma unroll
    for (int off = 32; off; off >>= 1) acc += __shfl_down(acc, off, 64);
    if (lane == 0) kv[row] = (float)acc;
}

// ---------------------------------------------------------------------------
// talking heads (8x8 over heads) + LIF -> kvs float {0,1}  (round-2 verbatim)
// ---------------------------------------------------------------------------
__global__ __launch_bounds__(256) void th_lif(const float* __restrict__ kvraw,
                                              const float* __restrict__ th,
                                              float* __restrict__ kvs)
{
    const int i = blockIdx.x * 256 + threadIdx.x;   // [0, B*C)
    const int b = i >> 9;
    const int c = i & 511;
    const int g = c >> 6;
    const int dd = c & 63;
    float v = 0.0f;
    #pragma unroll
    for (int t = 0; t < T_STEPS; ++t) {
        const float* base = kvraw + ((size_t)t * B_SZ + b) * C_IN;
        float x = 0.0f;
        #pragma unroll
        for (int hh = 0; hh < 8; ++hh)
            x += base[hh * 64 + dd] * th[g * 8 + hh];
        v += (x - v) * 0.5f;
        const float s = (v >= 0.5f) ? 1.0f : 0.0f;
        kvs[((size_t)t * B_SZ + b) * C_IN + c] = s;
        v = (s != 0.0f) ? 0.0f : v;
    }
}

extern "C" void kernel_launch(void* const* d_in, const int* in_sizes, int n_in,
                              void* d_out, int out_size, void* d_ws, size_t ws_size,
                              hipStream_t stream)
{
    const float* x       = (const float*)d_in[0];
    const float* q_w     = (const float*)d_in[1];
    const float* q_bn    = (const float*)d_in[2];
    const float* k_w     = (const float*)d_in[3];
    const float* k_bn    = (const float*)d_in[4];
    const float* v_w     = (const float*)d_in[5];
    const float* v_bn    = (const float*)d_in[6];
    const float* th_w    = (const float*)d_in[7];
    const float* proj_w  = (const float*)d_in[8];
    const float* proj_b  = (const float*)d_in[9];
    const float* proj_bn = (const float*)d_in[10];
    const float* fc1_w   = (const float*)d_in[11];
    const float* fc1_b   = (const float*)d_in[12];
    const float* fc1_bn  = (const float*)d_in[13];
    const float* fc2_w   = (const float*)d_in[14];
    const float* fc2_b   = (const float*)d_in[15];
    const float* fc2_bn  = (const float*)d_in[16];
    float* out = (float*)d_out;

    // workspace: round-2/6/7/9's proven 64 MiB + 128 KiB map
    u8* ws = (u8*)d_ws;
    const size_t SLOT = (size_t)T_STEPS * S_C;        // 16 MiB per u8 slot
    u8* xs = ws;                    // [TB][C][N] u8
    u8* qs = ws + SLOT;
    u8* ks = ws + 2 * SLOT;
    u8* vs = ws + 3 * SLOT;
    float* kvraw = (float*)(ws + 4 * SLOT);                 // [TB][C] f32 (64 KiB)
    float* kvsf  = kvraw + (size_t)T_STEPS * B_SZ * C_IN;   // [TB][C] f32 (64 KiB)
    u8* hdn = ws;                   // [TB][Ch][N] u8 = 64 MiB, reuses xs..vs (dead by fc1)

    // 1. xs = lif(x)
    lif_x_kernel<<<(int)(S_C / 256), 256, 0, stream>>>(x, xs);

    // 2. q/k/v = lif(bn(conv(xs)))  — fused triple GEMM
    //    grid = 8 n-slices * (8 co * 3 sel * 8 b) = 1536
    mm<0, 0, false, 512, 512, 3><<<1536, 256, 0, stream>>>(
        q_w, k_w, v_w, xs, q_bn, k_bn, v_bn, nullptr, nullptr, nullptr, qs, ks, vs);

    // 3. kv_raw = rowwise dot(k, v); 4. talking heads + lif -> kvs (float 0/1)
    kv_reduce<<<(T_STEPS * B_SZ * C_IN) / 4, 256, 0, stream>>>(ks, vs, kvraw);
    th_lif<<<(B_SZ * C_IN) / 256, 256, 0, stream>>>(kvraw, th_w, kvsf);

    // 5. xout = bn(proj(q * kvs) + b) + x  -> d_out (f32);  grid 8*(8*8)=512
    mm<1, 1, true, 512, 512, 1><<<512, 256, 0, stream>>>(
        proj_w, nullptr, nullptr, qs, proj_bn, nullptr, nullptr, proj_b, kvsf, x,
        out, nullptr, nullptr);

    // 6. hdn = lif(bn(fc1(xout) + b))  -> u8 spikes in ws;  grid 8*(32*8)=2048
    mm<0, 2, true, 512, 2048, 1><<<2048, 256, 0, stream>>>(
        fc1_w, nullptr, nullptr, out, fc1_bn, nullptr, nullptr, fc1_b, nullptr, nullptr,
        hdn, nullptr, nullptr);

    // 7. out = lif(bn(fc2(hdn) + b)) + xout  (in place on d_out);  grid 512
    mm<2, 0, true, 2048, 512, 1><<<512, 256, 0, stream>>>(
        fc2_w, nullptr, nullptr, hdn, fc2_bn, nullptr, nullptr, fc2_b, nullptr, nullptr,
        out, nullptr, nullptr);
}

// Round 11
// 3016.819 us; speedup vs baseline: 1.4439x; 1.4439x over previous
//
#include <hip/hip_runtime.h>

typedef unsigned char u8;
typedef unsigned int u32;

#define T_STEPS 4
#define B_SZ 8
#define C_IN 512
#define CH 2048
#define N_SP 1024
#define S_C ((size_t)B_SZ * C_IN * N_SP)    // elems per timestep

// ---------------------------------------------------------------------------
// lif_x: x [T,B,C,N] fp32 -> xs u8 spikes, same flat layout (round-2 verbatim).
// ---------------------------------------------------------------------------
__global__ __launch_bounds__(256) void lif_x_kernel(const float* __restrict__ in,
                                                    u8* __restrict__ out)
{
    size_t i = (size_t)blockIdx.x * 256 + threadIdx.x;
    float v = 0.0f;
    #pragma unroll
    for (int t = 0; t < T_STEPS; ++t) {
        float x = in[(size_t)t * S_C + i];
        v += (x - v) * 0.5f;
        u8 s = (v >= 0.5f) ? 1 : 0;
        out[(size_t)t * S_C + i] = s;
        v = s ? 0.0f : v;
    }
}

// ---------------------------------------------------------------------------
// Fused GEMM + BN (+bias) + LIF, fp32. Per-output math is ascending-k with a
// single fp32 accumulator -> bit-identical to rounds 2/6/7/9.
// Layouts: X [TB][K][N], W [CO][K] fp32, Y [TB][CO][N].
// MODE 0: LIF -> u8 spikes. MODE 1: y + res -> f32. MODE 2: LIF spike + in-place res -> f32.
// BSRC 0: u8 X. BSRC 1: u8 X * kvsf[k] at staging (proj mask). BSRC 2: f32 X (fc1).
// Tile 64co x 128n, BK=32 (round 11: halves barrier events per FMA vs BK=16),
// 256 threads, per-thread 4co x 8n. Single-buffered LDS (round 10 proved the
// double-buffer costs more in VGPR/LDS occupancy than one barrier saves).
// Register prefetch of next k-tile; u8 unpack at staging; nblk = bid & 7.
// NOTE: no min-waves hint (round 8: (256,4) clamps to 64 VGPR and spills).
// ---------------------------------------------------------------------------
template<int MODE, int BSRC, bool BIAS, int K, int CO, int NSEL>
__global__ __launch_bounds__(256) void mm(
    const float* __restrict__ W0, const float* __restrict__ W1, const float* __restrict__ W2,
    const void* __restrict__ Xv,
    const float* __restrict__ bn0, const float* __restrict__ bn1, const float* __restrict__ bn2,
    const float* __restrict__ bias,
    const float* __restrict__ kvsf,
    const float* __restrict__ res,
    void* Y0, void* Y1, void* Y2)
{
    constexpr int BM = 64;
    constexpr int NB_CO = CO / BM;
    constexpr int KT = K / 32;

    __shared__ float As[32][76];      // [k][co]  stride 76: 16B-aligned, <=2-way
    __shared__ float Xs[32][136];     // [k][n]

    const int bid = blockIdx.x;
    const int nblk = bid & 7;         // XCD-pinned n-slice
    int slot = bid >> 3;
    const int cb = slot % NB_CO; slot /= NB_CO;
    const int sel = (NSEL > 1) ? (slot % NSEL) : 0;
    const int b   = (NSEL > 1) ? (slot / NSEL) : slot;

    const float* W   = (NSEL == 1 || sel == 0) ? W0  : (sel == 1 ? W1  : W2);
    const float* bnp = (NSEL == 1 || sel == 0) ? bn0 : (sel == 1 ? bn1 : bn2);
    void* Yv         = (NSEL == 1 || sel == 0) ? Y0  : (sel == 1 ? Y1  : Y2);

    const int coBase = cb * BM;
    const int n0blk = nblk * 128;
    const int tid = threadIdx.x;
    const int tx = tid & 15, ty = tid >> 4;

    // staging indices: W rows by tid>>2 (8 k each); X rows ty and ty+16.
    const int wr = tid >> 2;
    const int wk8 = (tid & 3) * 8;

    // BN constants (round-2 expressions)
    float scale[4], shift[4];
    #pragma unroll
    for (int i = 0; i < 4; ++i) {
        const int co = coBase + ty * 4 + i;
        const float g = bnp[co], be = bnp[CO + co];
        const float mn = bnp[2 * CO + co], vr = bnp[3 * CO + co];
        scale[i] = g / sqrtf(vr + 1e-5f);
        shift[i] = be - mn * scale[i];
        if (BIAS) shift[i] += bias[co] * scale[i];
    }

    float vst[4][8];
    if (MODE != 1) {
        #pragma unroll
        for (int i = 0; i < 4; ++i)
            #pragma unroll
            for (int j = 0; j < 8; ++j) vst[i][j] = 0.0f;
    }

    for (int t = 0; t < T_STEPS; ++t) {
        const int tb = t * B_SZ + b;
        const u8* Xu = (const u8*)Xv + (size_t)tb * K * N_SP;
        const float* Xf = (const float*)Xv + (size_t)tb * K * N_SP;

        float acc[4][8];
        #pragma unroll
        for (int i = 0; i < 4; ++i)
            #pragma unroll
            for (int j = 0; j < 8; ++j) acc[i][j] = 0.0f;

        float4 wreg0, wreg1;
        u32 xa0, xb0, xa1, xb1;
        float mreg0 = 1.0f, mreg1 = 1.0f;
        float4 xf0a, xf0b, xf1a, xf1b;

        auto prefetch = [&](int kt) {
            const float* wp = W + (size_t)(coBase + wr) * K + kt * 32 + wk8;
            wreg0 = *reinterpret_cast<const float4*>(wp);
            wreg1 = *reinterpret_cast<const float4*>(wp + 4);
            if constexpr (BSRC <= 1) {
                const u8* xp0 = Xu + (size_t)(kt * 32 + ty) * N_SP + n0blk + tx * 4;
                const u8* xp1 = xp0 + (size_t)16 * N_SP;
                xa0 = *reinterpret_cast<const u32*>(xp0);
                xb0 = *reinterpret_cast<const u32*>(xp0 + 64);
                xa1 = *reinterpret_cast<const u32*>(xp1);
                xb1 = *reinterpret_cast<const u32*>(xp1 + 64);
                if constexpr (BSRC == 1) {
                    mreg0 = kvsf[(size_t)tb * K + kt * 32 + ty];
                    mreg1 = kvsf[(size_t)tb * K + kt * 32 + ty + 16];
                }
            } else {
                const float* xp0 = Xf + (size_t)(kt * 32 + ty) * N_SP + n0blk + tx * 4;
                const float* xp1 = xp0 + (size_t)16 * N_SP;
                xf0a = *reinterpret_cast<const float4*>(xp0);
                xf0b = *reinterpret_cast<const float4*>(xp0 + 64);
                xf1a = *reinterpret_cast<const float4*>(xp1);
                xf1b = *reinterpret_cast<const float4*>(xp1 + 64);
            }
        };

        prefetch(0);

        for (int kt = 0; kt < KT; ++kt) {
            __syncthreads();    // previous tile's compute done; LDS reusable
            As[wk8 + 0][wr] = wreg0.x;
            As[wk8 + 1][wr] = wreg0.y;
            As[wk8 + 2][wr] = wreg0.z;
            As[wk8 + 3][wr] = wreg0.w;
            As[wk8 + 4][wr] = wreg1.x;
            As[wk8 + 5][wr] = wreg1.y;
            As[wk8 + 6][wr] = wreg1.z;
            As[wk8 + 7][wr] = wreg1.w;
            if constexpr (BSRC <= 1) {
                float4 s0, s1, s2, s3;
                s0.x = (float)( xa0        & 0xFFu);
                s0.y = (float)((xa0 >> 8 ) & 0xFFu);
                s0.z = (float)((xa0 >> 16) & 0xFFu);
                s0.w = (float)( xa0 >> 24        );
                s1.x = (float)( xb0        & 0xFFu);
                s1.y = (float)((xb0 >> 8 ) & 0xFFu);
                s1.z = (float)((xb0 >> 16) & 0xFFu);
                s1.w = (float)( xb0 >> 24        );
                s2.x = (float)( xa1        & 0xFFu);
                s2.y = (float)((xa1 >> 8 ) & 0xFFu);
                s2.z = (float)((xa1 >> 16) & 0xFFu);
                s2.w = (float)( xa1 >> 24        );
                s3.x = (float)( xb1        & 0xFFu);
                s3.y = (float)((xb1 >> 8 ) & 0xFFu);
                s3.z = (float)((xb1 >> 16) & 0xFFu);
                s3.w = (float)( xb1 >> 24        );
                if constexpr (BSRC == 1) {
                    s0.x *= mreg0; s0.y *= mreg0; s0.z *= mreg0; s0.w *= mreg0;  // 0/1 x 0/1: exact
                    s1.x *= mreg0; s1.y *= mreg0; s1.z *= mreg0; s1.w *= mreg0;
                    s2.x *= mreg1; s2.y *= mreg1; s2.z *= mreg1; s2.w *= mreg1;
                    s3.x *= mreg1; s3.y *= mreg1; s3.z *= mreg1; s3.w *= mreg1;
                }
                *reinterpret_cast<float4*>(&Xs[ty][tx * 4]) = s0;
                *reinterpret_cast<float4*>(&Xs[ty][tx * 4 + 64]) = s1;
                *reinterpret_cast<float4*>(&Xs[ty + 16][tx * 4]) = s2;
                *reinterpret_cast<float4*>(&Xs[ty + 16][tx * 4 + 64]) = s3;
            } else {
                *reinterpret_cast<float4*>(&Xs[ty][tx * 4]) = xf0a;
                *reinterpret_cast<float4*>(&Xs[ty][tx * 4 + 64]) = xf0b;
                *reinterpret_cast<float4*>(&Xs[ty + 16][tx * 4]) = xf1a;
                *reinterpret_cast<float4*>(&Xs[ty + 16][tx * 4 + 64]) = xf1b;
            }
            __syncthreads();
            if (kt + 1 < KT) prefetch(kt + 1);   // overlaps with compute below

            #pragma unroll
            for (int kk = 0; kk < 32; ++kk) {
                float4 av = *reinterpret_cast<const float4*>(&As[kk][ty * 4]);
                float4 x0 = *reinterpret_cast<const float4*>(&Xs[kk][tx * 4]);
                float4 x1 = *reinterpret_cast<const float4*>(&Xs[kk][tx * 4 + 64]);
                float wa[4] = {av.x, av.y, av.z, av.w};
                float xw[8] = {x0.x, x0.y, x0.z, x0.w, x1.x, x1.y, x1.z, x1.w};
                #pragma unroll
                for (int i = 0; i < 4; ++i)
                    #pragma unroll
                    for (int j = 0; j < 8; ++j)
                        acc[i][j] += wa[i] * xw[j];   // ascending-k, single acc
            }
        }

        // epilogue for this timestep (round-2 expressions, bit-identical).
        // n positions: base (tx*4 + j) and base+64 (j = 4..7).
        #pragma unroll
        for (int i = 0; i < 4; ++i) {
            const int co = coBase + ty * 4 + i;
            const size_t base = ((size_t)tb * CO + co) * N_SP + n0blk + tx * 4;
            if constexpr (MODE == 0) {
                u32 p0 = 0, p1 = 0;
                #pragma unroll
                for (int j = 0; j < 8; ++j) {
                    const float y = acc[i][j] * scale[i] + shift[i];
                    float v = vst[i][j];
                    v += (y - v) * 0.5f;
                    const u32 s = (v >= 0.5f) ? 1u : 0u;
                    vst[i][j] = s ? 0.0f : v;
                    if (j < 4) p0 |= s << (8 * j); else p1 |= s << (8 * (j - 4));
                }
                *reinterpret_cast<u32*>((u8*)Yv + base) = p0;
                *reinterpret_cast<u32*>((u8*)Yv + base + 64) = p1;
            } else if constexpr (MODE == 1) {
                float4 r0 = *reinterpret_cast<const float4*>(res + base);
                float4 r1 = *reinterpret_cast<const float4*>(res + base + 64);
                float rr[8] = {r0.x, r0.y, r0.z, r0.w, r1.x, r1.y, r1.z, r1.w};
                float o[8];
                #pragma unroll
                for (int j = 0; j < 8; ++j)
                    o[j] = acc[i][j] * scale[i] + shift[i] + rr[j];
                float4 s0 = {o[0], o[1], o[2], o[3]};
                float4 s1 = {o[4], o[5], o[6], o[7]};
                *reinterpret_cast<float4*>((float*)Yv + base) = s0;
                *reinterpret_cast<float4*>((float*)Yv + base + 64) = s1;
            } else {
                float* op = (float*)Yv + base;
                float4 r0 = *reinterpret_cast<const float4*>(op);
                float4 r1 = *reinterpret_cast<const float4*>(op + 64);
                float rr[8] = {r0.x, r0.y, r0.z, r0.w, r1.x, r1.y, r1.z, r1.w};
                float o[8];
                #pragma unroll
                for (int j = 0; j < 8; ++j) {
                    const float y = acc[i][j] * scale[i] + shift[i];
                    float v = vst[i][j];
                    v += (y - v) * 0.5f;
                    const u32 s = (v >= 0.5f) ? 1u : 0u;
                    vst[i][j] = s ? 0.0f : v;
                    o[j] = rr[j] + (s ? 1.0f : 0.0f);
                }
                float4 s0 = {o[0], o[1], o[2], o[3]};
                float4 s1 = {o[4], o[5], o[6], o[7]};
                *reinterpret_cast<float4*>(op) = s0;
                *reinterpret_cast<float4*>(op + 64) = s1;
            }
        }
    }
}

// ---------------------------------------------------------------------------
// kv_raw[row=tb*C+c] = sum_n k*v  (exact integer; round-2 verbatim)
// ---------------------------------------------------------------------------
__global__ __launch_bounds__(256) void kv_reduce(const u8* __restrict__ ks,
                                                 const u8* __restrict__ vs,
                                                 float* __restrict__ kv)
{
    const int row = blockIdx.x * 4 + (threadIdx.x >> 6);  // [0, T*B*C)
    const int lane = threadIdx.x & 63;
    const u8* kp = ks + (size_t)row * N_SP;
    const u8* vp = vs + (size_t)row * N_SP;
    int acc = 0;
    #pragma unroll
    for (int n = 0; n < N_SP; n += 256) {
        uchar4 a = *reinterpret_cast<const uchar4*>(kp + n + lane * 4);
        uchar4 c = *reinterpret_cast<const uchar4*>(vp + n + lane * 4);
        acc += (a.x & c.x) + (a.y & c.y) + (a.z & c.z) + (a.w & c.w);
    }
    #pragma unroll
    for (int off = 32; off; off >>= 1) acc += __shfl_down(acc, off, 64);
    if (lane == 0) kv[row] = (float)acc;
}

// ---------------------------------------------------------------------------
// talking heads (8x8 over heads) + LIF -> kvs float {0,1}  (round-2 verbatim)
// ---------------------------------------------------------------------------
__global__ __launch_bounds__(256) void th_lif(const float* __restrict__ kvraw,
                                              const float* __restrict__ th,
                                              float* __restrict__ kvs)
{
    const int i = blockIdx.x * 256 + threadIdx.x;   // [0, B*C)
    const int b = i >> 9;
    const int c = i & 511;
    const int g = c >> 6;
    const int dd = c & 63;
    float v = 0.0f;
    #pragma unroll
    for (int t = 0; t < T_STEPS; ++t) {
        const float* base = kvraw + ((size_t)t * B_SZ + b) * C_IN;
        float x = 0.0f;
        #pragma unroll
        for (int hh = 0; hh < 8; ++hh)
            x += base[hh * 64 + dd] * th[g * 8 + hh];
        v += (x - v) * 0.5f;
        const float s = (v >= 0.5f) ? 1.0f : 0.0f;
        kvs[((size_t)t * B_SZ + b) * C_IN + c] = s;
        v = (s != 0.0f) ? 0.0f : v;
    }
}

extern "C" void kernel_launch(void* const* d_in, const int* in_sizes, int n_in,
                              void* d_out, int out_size, void* d_ws, size_t ws_size,
                              hipStream_t stream)
{
    const float* x       = (const float*)d_in[0];
    const float* q_w     = (const float*)d_in[1];
    const float* q_bn    = (const float*)d_in[2];
    const float* k_w     = (const float*)d_in[3];
    const float* k_bn    = (const float*)d_in[4];
    const float* v_w     = (const float*)d_in[5];
    const float* v_bn    = (const float*)d_in[6];
    const float* th_w    = (const float*)d_in[7];
    const float* proj_w  = (const float*)d_in[8];
    const float* proj_b  = (const float*)d_in[9];
    const float* proj_bn = (const float*)d_in[10];
    const float* fc1_w   = (const float*)d_in[11];
    const float* fc1_b   = (const float*)d_in[12];
    const float* fc1_bn  = (const float*)d_in[13];
    const float* fc2_w   = (const float*)d_in[14];
    const float* fc2_b   = (const float*)d_in[15];
    const float* fc2_bn  = (const float*)d_in[16];
    float* out = (float*)d_out;

    // workspace: round-2/6/7/9's proven 64 MiB + 128 KiB map
    u8* ws = (u8*)d_ws;
    const size_t SLOT = (size_t)T_STEPS * S_C;        // 16 MiB per u8 slot
    u8* xs = ws;                    // [TB][C][N] u8
    u8* qs = ws + SLOT;
    u8* ks = ws + 2 * SLOT;
    u8* vs = ws + 3 * SLOT;
    float* kvraw = (float*)(ws + 4 * SLOT);                 // [TB][C] f32 (64 KiB)
    float* kvsf  = kvraw + (size_t)T_STEPS * B_SZ * C_IN;   // [TB][C] f32 (64 KiB)
    u8* hdn = ws;                   // [TB][Ch][N] u8 = 64 MiB, reuses xs..vs (dead by fc1)

    // 1. xs = lif(x)
    lif_x_kernel<<<(int)(S_C / 256), 256, 0, stream>>>(x, xs);

    // 2. q/k/v = lif(bn(conv(xs)))  — fused triple GEMM
    //    grid = 8 n-slices * (8 co * 3 sel * 8 b) = 1536
    mm<0, 0, false, 512, 512, 3><<<1536, 256, 0, stream>>>(
        q_w, k_w, v_w, xs, q_bn, k_bn, v_bn, nullptr, nullptr, nullptr, qs, ks, vs);

    // 3. kv_raw = rowwise dot(k, v); 4. talking heads + lif -> kvs (float 0/1)
    kv_reduce<<<(T_STEPS * B_SZ * C_IN) / 4, 256, 0, stream>>>(ks, vs, kvraw);
    th_lif<<<(B_SZ * C_IN) / 256, 256, 0, stream>>>(kvraw, th_w, kvsf);

    // 5. xout = bn(proj(q * kvs) + b) + x  -> d_out (f32);  grid 8*(8*8)=512
    mm<1, 1, true, 512, 512, 1><<<512, 256, 0, stream>>>(
        proj_w, nullptr, nullptr, qs, proj_bn, nullptr, nullptr, proj_b, kvsf, x,
        out, nullptr, nullptr);

    // 6. hdn = lif(bn(fc1(xout) + b))  -> u8 spikes in ws;  grid 8*(32*8)=2048
    mm<0, 2, true, 512, 2048, 1><<<2048, 256, 0, stream>>>(
        fc1_w, nullptr, nullptr, out, fc1_bn, nullptr, nullptr, fc1_b, nullptr, nullptr,
        hdn, nullptr, nullptr);

    // 7. out = lif(bn(fc2(hdn) + b)) + xout  (in place on d_out);  grid 512
    mm<2, 0, true, 2048, 512, 1><<<512, 256, 0, stream>>>(
        fc2_w, nullptr, nullptr, hdn, fc2_bn, nullptr, nullptr, fc2_b, nullptr, nullptr,
        out, nullptr, nullptr);
}

// Round 12
// 2850.798 us; speedup vs baseline: 1.5280x; 1.0582x over previous
//
#include <hip/hip_runtime.h>

typedef unsigned char u8;
typedef unsigned int u32;

#define T_STEPS 4
#define B_SZ 8
#define C_IN 512
#define CH 2048
#define N_SP 1024
#define S_C ((size_t)B_SZ * C_IN * N_SP)    // elems per timestep

// ---------------------------------------------------------------------------
// lif_x: x [T,B,C,N] fp32 -> xs u8 spikes, same flat layout (round-2 verbatim).
// ---------------------------------------------------------------------------
__global__ __launch_bounds__(256) void lif_x_kernel(const float* __restrict__ in,
                                                    u8* __restrict__ out)
{
    size_t i = (size_t)blockIdx.x * 256 + threadIdx.x;
    float v = 0.0f;
    #pragma unroll
    for (int t = 0; t < T_STEPS; ++t) {
        float x = in[(size_t)t * S_C + i];
        v += (x - v) * 0.5f;
        u8 s = (v >= 0.5f) ? 1 : 0;
        out[(size_t)t * S_C + i] = s;
        v = s ? 0.0f : v;
    }
}

// ---------------------------------------------------------------------------
// Fused GEMM + BN (+bias) + LIF, fp32. Per-output math is ascending-k with a
// single fp32 accumulator -> bit-identical to rounds 2/6/7/9.
// Layouts: X [TB][K][N], W [CO][K] fp32, Y [TB][CO][N].
// MODE 0: LIF -> u8 spikes. MODE 1: y + res -> f32. MODE 2: LIF spike + in-place res -> f32.
// BSRC 0: u8 X. BSRC 1: u8 X * kvsf[k] at staging (proj mask). BSRC 2: f32 X (fc1).
// TN = n-elems per thread (8 or 4): tile 64co x (16*TN)n, 256 threads,
// per-thread 4co x TN n. BK=16, single-buffered LDS (round 10/11: anything
// that raises VGPR past ~112 or LDS past ~14KB loses occupancy and net time).
// TN=4 exists because fc2's grid at TN=8 is 512 blocks = 2/CU = 25% occupancy
// cap (round 9 profile: fc1/fc2 at 42% of FMA floor; qkv at 80% with 6/CU).
// Register prefetch of next k-tile; u8 unpack at staging; XCD-friendly bid%NB_N.
// NOTE: no min-waves hint (round 8: (256,4) clamps to 64 VGPR and spills).
// ---------------------------------------------------------------------------
template<int TN, int MODE, int BSRC, bool BIAS, int K, int CO, int NSEL>
__global__ __launch_bounds__(256) void mm(
    const float* __restrict__ W0, const float* __restrict__ W1, const float* __restrict__ W2,
    const void* __restrict__ Xv,
    const float* __restrict__ bn0, const float* __restrict__ bn1, const float* __restrict__ bn2,
    const float* __restrict__ bias,
    const float* __restrict__ kvsf,
    const float* __restrict__ res,
    void* Y0, void* Y1, void* Y2)
{
    constexpr int BM = 64;
    constexpr int BN = 16 * TN;
    constexpr int NB_CO = CO / BM;
    constexpr int NB_N = N_SP / BN;
    constexpr int KT = K / 16;
    constexpr int XSTR = (TN == 8) ? 136 : 72;   // 16B-aligned strides

    __shared__ float As[16][76];      // [k][co]
    __shared__ float Xs[16][XSTR];    // [k][n]

    const int bid = blockIdx.x;
    const int nblk = bid % NB_N;      // co-blocks sharing (nblk,b) land on same XCD
    int slot = bid / NB_N;
    const int cb = slot % NB_CO; slot /= NB_CO;
    const int sel = (NSEL > 1) ? (slot % NSEL) : 0;
    const int b   = (NSEL > 1) ? (slot / NSEL) : slot;

    const float* W   = (NSEL == 1 || sel == 0) ? W0  : (sel == 1 ? W1  : W2);
    const float* bnp = (NSEL == 1 || sel == 0) ? bn0 : (sel == 1 ? bn1 : bn2);
    void* Yv         = (NSEL == 1 || sel == 0) ? Y0  : (sel == 1 ? Y1  : Y2);

    const int coBase = cb * BM;
    const int n0blk = nblk * BN;
    const int tid = threadIdx.x;
    const int tx = tid & 15, ty = tid >> 4;

    // staging indices: W rows by tid>>2; X row = ty, cols tx*4 (+64 if TN=8)
    const int wr = tid >> 2;
    const int wk4 = (tid & 3) * 4;

    // BN constants (round-2 expressions)
    float scale[4], shift[4];
    #pragma unroll
    for (int i = 0; i < 4; ++i) {
        const int co = coBase + ty * 4 + i;
        const float g = bnp[co], be = bnp[CO + co];
        const float mn = bnp[2 * CO + co], vr = bnp[3 * CO + co];
        scale[i] = g / sqrtf(vr + 1e-5f);
        shift[i] = be - mn * scale[i];
        if (BIAS) shift[i] += bias[co] * scale[i];
    }

    float vst[4][TN];
    if (MODE != 1) {
        #pragma unroll
        for (int i = 0; i < 4; ++i)
            #pragma unroll
            for (int j = 0; j < TN; ++j) vst[i][j] = 0.0f;
    }

    for (int t = 0; t < T_STEPS; ++t) {
        const int tb = t * B_SZ + b;
        const u8* Xu = (const u8*)Xv + (size_t)tb * K * N_SP;
        const float* Xf = (const float*)Xv + (size_t)tb * K * N_SP;

        float acc[4][TN];
        #pragma unroll
        for (int i = 0; i < 4; ++i)
            #pragma unroll
            for (int j = 0; j < TN; ++j) acc[i][j] = 0.0f;

        float4 wreg;
        u32 xa = 0, xb = 0;
        float mreg = 1.0f;
        float4 xfa, xfb;

        auto prefetch = [&](int kt) {
            wreg = *reinterpret_cast<const float4*>(
                W + (size_t)(coBase + wr) * K + kt * 16 + wk4);
            if constexpr (BSRC <= 1) {
                const u8* xp = Xu + (size_t)(kt * 16 + ty) * N_SP + n0blk + tx * 4;
                xa = *reinterpret_cast<const u32*>(xp);
                if constexpr (TN == 8)
                    xb = *reinterpret_cast<const u32*>(xp + 64);
                if constexpr (BSRC == 1)
                    mreg = kvsf[(size_t)tb * K + kt * 16 + ty];
            } else {
                const float* xp = Xf + (size_t)(kt * 16 + ty) * N_SP + n0blk + tx * 4;
                xfa = *reinterpret_cast<const float4*>(xp);
                if constexpr (TN == 8)
                    xfb = *reinterpret_cast<const float4*>(xp + 64);
            }
        };

        prefetch(0);

        for (int kt = 0; kt < KT; ++kt) {
            __syncthreads();    // previous tile's compute done; LDS reusable
            As[wk4 + 0][wr] = wreg.x;
            As[wk4 + 1][wr] = wreg.y;
            As[wk4 + 2][wr] = wreg.z;
            As[wk4 + 3][wr] = wreg.w;
            if constexpr (BSRC <= 1) {
                float4 s0;
                s0.x = (float)( xa        & 0xFFu);
                s0.y = (float)((xa >> 8 ) & 0xFFu);
                s0.z = (float)((xa >> 16) & 0xFFu);
                s0.w = (float)( xa >> 24        );
                if constexpr (BSRC == 1) {
                    s0.x *= mreg; s0.y *= mreg; s0.z *= mreg; s0.w *= mreg;   // 0/1 x 0/1: exact
                }
                *reinterpret_cast<float4*>(&Xs[ty][tx * 4]) = s0;
                if constexpr (TN == 8) {
                    float4 s1;
                    s1.x = (float)( xb        & 0xFFu);
                    s1.y = (float)((xb >> 8 ) & 0xFFu);
                    s1.z = (float)((xb >> 16) & 0xFFu);
                    s1.w = (float)( xb >> 24        );
                    if constexpr (BSRC == 1) {
                        s1.x *= mreg; s1.y *= mreg; s1.z *= mreg; s1.w *= mreg;
                    }
                    *reinterpret_cast<float4*>(&Xs[ty][tx * 4 + 64]) = s1;
                }
            } else {
                *reinterpret_cast<float4*>(&Xs[ty][tx * 4]) = xfa;
                if constexpr (TN == 8)
                    *reinterpret_cast<float4*>(&Xs[ty][tx * 4 + 64]) = xfb;
            }
            __syncthreads();
            if (kt + 1 < KT) prefetch(kt + 1);   // overlaps with compute below

            #pragma unroll
            for (int kk = 0; kk < 16; ++kk) {
                float4 av = *reinterpret_cast<const float4*>(&As[kk][ty * 4]);
                float4 x0 = *reinterpret_cast<const float4*>(&Xs[kk][tx * 4]);
                float wa[4] = {av.x, av.y, av.z, av.w};
                float xw[8];
                xw[0] = x0.x; xw[1] = x0.y; xw[2] = x0.z; xw[3] = x0.w;
                if constexpr (TN == 8) {
                    float4 x1 = *reinterpret_cast<const float4*>(&Xs[kk][tx * 4 + 64]);
                    xw[4] = x1.x; xw[5] = x1.y; xw[6] = x1.z; xw[7] = x1.w;
                }
                #pragma unroll
                for (int i = 0; i < 4; ++i)
                    #pragma unroll
                    for (int j = 0; j < TN; ++j)
                        acc[i][j] += wa[i] * xw[j];   // ascending-k, single acc
            }
        }

        // epilogue for this timestep (round-2 expressions, bit-identical).
        // n chunks: base + h*64, elems j = h*4 .. h*4+3.
        #pragma unroll
        for (int i = 0; i < 4; ++i) {
            const int co = coBase + ty * 4 + i;
            const size_t base = ((size_t)tb * CO + co) * N_SP + n0blk + tx * 4;
            #pragma unroll
            for (int h = 0; h < TN / 4; ++h) {
                const size_t off = base + h * 64;
                if constexpr (MODE == 0) {
                    u32 pk = 0;
                    #pragma unroll
                    for (int e = 0; e < 4; ++e) {
                        const int j = h * 4 + e;
                        const float y = acc[i][j] * scale[i] + shift[i];
                        float v = vst[i][j];
                        v += (y - v) * 0.5f;
                        const u32 s = (v >= 0.5f) ? 1u : 0u;
                        vst[i][j] = s ? 0.0f : v;
                        pk |= s << (8 * e);
                    }
                    *reinterpret_cast<u32*>((u8*)Yv + off) = pk;
                } else if constexpr (MODE == 1) {
                    float4 r0 = *reinterpret_cast<const float4*>(res + off);
                    float rr[4] = {r0.x, r0.y, r0.z, r0.w};
                    float o[4];
                    #pragma unroll
                    for (int e = 0; e < 4; ++e)
                        o[e] = acc[i][h * 4 + e] * scale[i] + shift[i] + rr[e];
                    float4 s0 = {o[0], o[1], o[2], o[3]};
                    *reinterpret_cast<float4*>((float*)Yv + off) = s0;
                } else {
                    float* op = (float*)Yv + off;
                    float4 r0 = *reinterpret_cast<const float4*>(op);
                    float rr[4] = {r0.x, r0.y, r0.z, r0.w};
                    float o[4];
                    #pragma unroll
                    for (int e = 0; e < 4; ++e) {
                        const int j = h * 4 + e;
                        const float y = acc[i][j] * scale[i] + shift[i];
                        float v = vst[i][j];
                        v += (y - v) * 0.5f;
                        const u32 s = (v >= 0.5f) ? 1u : 0u;
                        vst[i][j] = s ? 0.0f : v;
                        o[e] = rr[e] + (s ? 1.0f : 0.0f);
                    }
                    float4 s0 = {o[0], o[1], o[2], o[3]};
                    *reinterpret_cast<float4*>(op) = s0;
                }
            }
        }
    }
}

// ---------------------------------------------------------------------------
// kv_raw[row=tb*C+c] = sum_n k*v  (exact integer; round-2 verbatim)
// ---------------------------------------------------------------------------
__global__ __launch_bounds__(256) void kv_reduce(const u8* __restrict__ ks,
                                                 const u8* __restrict__ vs,
                                                 float* __restrict__ kv)
{
    const int row = blockIdx.x * 4 + (threadIdx.x >> 6);  // [0, T*B*C)
    const int lane = threadIdx.x & 63;
    const u8* kp = ks + (size_t)row * N_SP;
    const u8* vp = vs + (size_t)row * N_SP;
    int acc = 0;
    #pragma unroll
    for (int n = 0; n < N_SP; n += 256) {
        uchar4 a = *reinterpret_cast<const uchar4*>(kp + n + lane * 4);
        uchar4 c = *reinterpret_cast<const uchar4*>(vp + n + lane * 4);
        acc += (a.x & c.x) + (a.y & c.y) + (a.z & c.z) + (a.w & c.w);
    }
    #pragma unroll
    for (int off = 32; off; off >>= 1) acc += __shfl_down(acc, off, 64);
    if (lane == 0) kv[row] = (float)acc;
}

// ---------------------------------------------------------------------------
// talking heads (8x8 over heads) + LIF -> kvs float {0,1}  (round-2 verbatim)
// ---------------------------------------------------------------------------
__global__ __launch_bounds__(256) void th_lif(const float* __restrict__ kvraw,
                                              const float* __restrict__ th,
                                              float* __restrict__ kvs)
{
    const int i = blockIdx.x * 256 + threadIdx.x;   // [0, B*C)
    const int b = i >> 9;
    const int c = i & 511;
    const int g = c >> 6;
    const int dd = c & 63;
    float v = 0.0f;
    #pragma unroll
    for (int t = 0; t < T_STEPS; ++t) {
        const float* base = kvraw + ((size_t)t * B_SZ + b) * C_IN;
        float x = 0.0f;
        #pragma unroll
        for (int hh = 0; hh < 8; ++hh)
            x += base[hh * 64 + dd] * th[g * 8 + hh];
        v += (x - v) * 0.5f;
        const float s = (v >= 0.5f) ? 1.0f : 0.0f;
        kvs[((size_t)t * B_SZ + b) * C_IN + c] = s;
        v = (s != 0.0f) ? 0.0f : v;
    }
}

extern "C" void kernel_launch(void* const* d_in, const int* in_sizes, int n_in,
                              void* d_out, int out_size, void* d_ws, size_t ws_size,
                              hipStream_t stream)
{
    const float* x       = (const float*)d_in[0];
    const float* q_w     = (const float*)d_in[1];
    const float* q_bn    = (const float*)d_in[2];
    const float* k_w     = (const float*)d_in[3];
    const float* k_bn    = (const float*)d_in[4];
    const float* v_w     = (const float*)d_in[5];
    const float* v_bn    = (const float*)d_in[6];
    const float* th_w    = (const float*)d_in[7];
    const float* proj_w  = (const float*)d_in[8];
    const float* proj_b  = (const float*)d_in[9];
    const float* proj_bn = (const float*)d_in[10];
    const float* fc1_w   = (const float*)d_in[11];
    const float* fc1_b   = (const float*)d_in[12];
    const float* fc1_bn  = (const float*)d_in[13];
    const float* fc2_w   = (const float*)d_in[14];
    const float* fc2_b   = (const float*)d_in[15];
    const float* fc2_bn  = (const float*)d_in[16];
    float* out = (float*)d_out;

    // workspace: round-2/6/7/9's proven 64 MiB + 128 KiB map
    u8* ws = (u8*)d_ws;
    const size_t SLOT = (size_t)T_STEPS * S_C;        // 16 MiB per u8 slot
    u8* xs = ws;                    // [TB][C][N] u8
    u8* qs = ws + SLOT;
    u8* ks = ws + 2 * SLOT;
    u8* vs = ws + 3 * SLOT;
    float* kvraw = (float*)(ws + 4 * SLOT);                 // [TB][C] f32 (64 KiB)
    float* kvsf  = kvraw + (size_t)T_STEPS * B_SZ * C_IN;   // [TB][C] f32 (64 KiB)
    u8* hdn = ws;                   // [TB][Ch][N] u8 = 64 MiB, reuses xs..vs (dead by fc1)

    // 1. xs = lif(x)
    lif_x_kernel<<<(int)(S_C / 256), 256, 0, stream>>>(x, xs);

    // 2. q/k/v = lif(bn(conv(xs)))  — fused triple GEMM, TN=8 (proven ~80% of floor)
    //    grid = 8 n-slices * (8 co * 3 sel * 8 b) = 1536
    mm<8, 0, 0, false, 512, 512, 3><<<1536, 256, 0, stream>>>(
        q_w, k_w, v_w, xs, q_bn, k_bn, v_bn, nullptr, nullptr, nullptr, qs, ks, vs);

    // 3. kv_raw = rowwise dot(k, v); 4. talking heads + lif -> kvs (float 0/1)
    kv_reduce<<<(T_STEPS * B_SZ * C_IN) / 4, 256, 0, stream>>>(ks, vs, kvraw);
    th_lif<<<(B_SZ * C_IN) / 256, 256, 0, stream>>>(kvraw, th_w, kvsf);

    // 5. xout = bn(proj(q * kvs) + b) + x  -> d_out; TN=4, grid 16*8*8 = 1024
    mm<4, 1, 1, true, 512, 512, 1><<<1024, 256, 0, stream>>>(
        proj_w, nullptr, nullptr, qs, proj_bn, nullptr, nullptr, proj_b, kvsf, x,
        out, nullptr, nullptr);

    // 6. hdn = lif(bn(fc1(xout) + b)); TN=4, grid 16*32*8 = 4096
    mm<4, 0, 2, true, 512, 2048, 1><<<4096, 256, 0, stream>>>(
        fc1_w, nullptr, nullptr, out, fc1_bn, nullptr, nullptr, fc1_b, nullptr, nullptr,
        hdn, nullptr, nullptr);

    // 7. out = lif(bn(fc2(hdn) + b)) + xout  (in place); TN=4, grid 16*8*8 = 1024
    mm<4, 2, 0, true, 2048, 512, 1><<<1024, 256, 0, stream>>>(
        fc2_w, nullptr, nullptr, hdn, fc2_bn, nullptr, nullptr, fc2_b, nullptr, nullptr,
        out, nullptr, nullptr);
}

// Round 13
// 2390.433 us; speedup vs baseline: 1.8222x; 1.1926x over previous
//
#include <hip/hip_runtime.h>

typedef unsigned char u8;
typedef unsigned int u32;

#define T_STEPS 4
#define B_SZ 8
#define C_IN 512
#define CH 2048
#define N_SP 1024
#define S_C ((size_t)B_SZ * C_IN * N_SP)    // elems per timestep

// ---------------------------------------------------------------------------
// lif_x: x [T,B,C,N] fp32 -> xs u8 spikes, same flat layout (round-2 verbatim).
// ---------------------------------------------------------------------------
__global__ __launch_bounds__(256) void lif_x_kernel(const float* __restrict__ in,
                                                    u8* __restrict__ out)
{
    size_t i = (size_t)blockIdx.x * 256 + threadIdx.x;
    float v = 0.0f;
    #pragma unroll
    for (int t = 0; t < T_STEPS; ++t) {
        float x = in[(size_t)t * S_C + i];
        v += (x - v) * 0.5f;
        u8 s = (v >= 0.5f) ? 1 : 0;
        out[(size_t)t * S_C + i] = s;
        v = s ? 0.0f : v;
    }
}

// ---------------------------------------------------------------------------
// Fused GEMM + BN (+bias) + LIF, fp32, T-FOLDED (round 13):
// each block computes 64co x 64n for ALL 4 timesteps in ONE k-sweep.
//   - W tile staged once per k-tile (was 4x in the t-outer form)
//   - 4 X tiles (one per t) staged per k-tile; barriers per FMA halved
//   - LIF membrane chain runs in the epilogue over completed accumulators
//     (ascending t) -> vst register array eliminated
// Per output element: ascending-k, single fp32 accumulator; epilogue
// expressions identical to rounds 2/6/9 -> bit-identical output.
// Layouts: X [TB][K][N], W [CO][K] fp32, Y [TB][CO][N].
// MODE 0: LIF -> u8 spikes. MODE 1: y + res -> f32. MODE 2: LIF spike + in-place res -> f32.
// BSRC 0: u8 X. BSRC 1: u8 X * kvsf[t][k] at staging (proj mask). BSRC 2: f32 X (fc1).
// 256 threads, per-thread 4co x 4n x 4t. BK=16. Single-buffered LDS.
// NOTE: no min-waves hint (round 8: (256,4) clamps to 64 VGPR and spills).
// ---------------------------------------------------------------------------
template<int MODE, int BSRC, bool BIAS, int K, int CO, int NSEL>
__global__ __launch_bounds__(256) void mm(
    const float* __restrict__ W0, const float* __restrict__ W1, const float* __restrict__ W2,
    const void* __restrict__ Xv,
    const float* __restrict__ bn0, const float* __restrict__ bn1, const float* __restrict__ bn2,
    const float* __restrict__ bias,
    const float* __restrict__ kvsf,
    const float* __restrict__ res,
    void* Y0, void* Y1, void* Y2)
{
    constexpr int NB_CO = CO / 64;
    constexpr int NB_N = N_SP / 64;   // 16
    constexpr int KT = K / 16;

    __shared__ float As[16][68];      // [k][co]     broadcast reads
    __shared__ float Xs[4][16][68];   // [t][k][n]   2-way max on write/read

    const int bid = blockIdx.x;
    const int nblk = bid % NB_N;      // co-blocks sharing (nblk,b) land on same XCD (16%8==0)
    int slot = bid / NB_N;
    const int cb = slot % NB_CO; slot /= NB_CO;
    const int sel = (NSEL > 1) ? (slot % NSEL) : 0;
    const int b   = (NSEL > 1) ? (slot / NSEL) : slot;

    const float* W   = (NSEL == 1 || sel == 0) ? W0  : (sel == 1 ? W1  : W2);
    const float* bnp = (NSEL == 1 || sel == 0) ? bn0 : (sel == 1 ? bn1 : bn2);
    void* Yv         = (NSEL == 1 || sel == 0) ? Y0  : (sel == 1 ? Y1  : Y2);

    const int coBase = cb * 64;
    const int n0blk = nblk * 64;
    const int tid = threadIdx.x;
    const int tx = tid & 15, ty = tid >> 4;

    // staging indices: W row = tid>>2 (4 k each); X row = ty, col seg = tx*4
    const int wr = tid >> 2;
    const int wk4 = (tid & 3) * 4;

    // BN constants (round-2 expressions)
    float scale[4], shift[4];
    #pragma unroll
    for (int i = 0; i < 4; ++i) {
        const int co = coBase + ty * 4 + i;
        const float g = bnp[co], be = bnp[CO + co];
        const float mn = bnp[2 * CO + co], vr = bnp[3 * CO + co];
        scale[i] = g / sqrtf(vr + 1e-5f);
        shift[i] = be - mn * scale[i];
        if (BIAS) shift[i] += bias[co] * scale[i];
    }

    float acc[4][4][4];   // [t][co i][n j]
    #pragma unroll
    for (int t = 0; t < 4; ++t)
        #pragma unroll
        for (int i = 0; i < 4; ++i)
            #pragma unroll
            for (int j = 0; j < 4; ++j) acc[t][i][j] = 0.0f;

    float4 wreg;
    u32 xu[4];
    float mreg[4];
    float4 xf[4];

    auto prefetch = [&](int kt) {
        wreg = *reinterpret_cast<const float4*>(
            W + (size_t)(coBase + wr) * K + kt * 16 + wk4);
        #pragma unroll
        for (int t = 0; t < 4; ++t) {
            const int tb = t * B_SZ + b;
            if constexpr (BSRC <= 1) {
                xu[t] = *reinterpret_cast<const u32*>(
                    (const u8*)Xv + (size_t)tb * K * N_SP
                    + (size_t)(kt * 16 + ty) * N_SP + n0blk + tx * 4);
                if constexpr (BSRC == 1)
                    mreg[t] = kvsf[(size_t)tb * K + kt * 16 + ty];
            } else {
                xf[t] = *reinterpret_cast<const float4*>(
                    (const float*)Xv + (size_t)tb * K * N_SP
                    + (size_t)(kt * 16 + ty) * N_SP + n0blk + tx * 4);
            }
        }
    };

    prefetch(0);

    for (int kt = 0; kt < KT; ++kt) {
        __syncthreads();    // previous tile's compute done; LDS reusable
        As[wk4 + 0][wr] = wreg.x;
        As[wk4 + 1][wr] = wreg.y;
        As[wk4 + 2][wr] = wreg.z;
        As[wk4 + 3][wr] = wreg.w;
        #pragma unroll
        for (int t = 0; t < 4; ++t) {
            float4 s0;
            if constexpr (BSRC <= 1) {
                s0.x = (float)( xu[t]        & 0xFFu);
                s0.y = (float)((xu[t] >> 8 ) & 0xFFu);
                s0.z = (float)((xu[t] >> 16) & 0xFFu);
                s0.w = (float)( xu[t] >> 24        );
                if constexpr (BSRC == 1) {
                    s0.x *= mreg[t]; s0.y *= mreg[t];   // 0/1 x 0/1: exact
                    s0.z *= mreg[t]; s0.w *= mreg[t];
                }
            } else {
                s0 = xf[t];
            }
            *reinterpret_cast<float4*>(&Xs[t][ty][tx * 4]) = s0;
        }
        __syncthreads();
        if (kt + 1 < KT) prefetch(kt + 1);   // overlaps with compute below

        #pragma unroll
        for (int kk = 0; kk < 16; ++kk) {
            float4 av = *reinterpret_cast<const float4*>(&As[kk][ty * 4]);
            float wa[4] = {av.x, av.y, av.z, av.w};
            #pragma unroll
            for (int t = 0; t < 4; ++t) {
                float4 xv = *reinterpret_cast<const float4*>(&Xs[t][kk][tx * 4]);
                float xw[4] = {xv.x, xv.y, xv.z, xv.w};
                #pragma unroll
                for (int i = 0; i < 4; ++i)
                    #pragma unroll
                    for (int j = 0; j < 4; ++j)
                        acc[t][i][j] += wa[i] * xw[j];   // ascending-k, single acc
            }
        }
    }

    // epilogue: LIF chain over t (ascending), expressions identical to round 2.
    #pragma unroll
    for (int i = 0; i < 4; ++i) {
        const int co = coBase + ty * 4 + i;
        float v[4] = {0.0f, 0.0f, 0.0f, 0.0f};
        #pragma unroll
        for (int t = 0; t < 4; ++t) {
            const int tb = t * B_SZ + b;
            const size_t off = ((size_t)tb * CO + co) * N_SP + n0blk + tx * 4;
            if constexpr (MODE == 0) {
                u32 pk = 0;
                #pragma unroll
                for (int e = 0; e < 4; ++e) {
                    const float y = acc[t][i][e] * scale[i] + shift[i];
                    v[e] += (y - v[e]) * 0.5f;
                    const u32 s = (v[e] >= 0.5f) ? 1u : 0u;
                    v[e] = s ? 0.0f : v[e];
                    pk |= s << (8 * e);
                }
                *reinterpret_cast<u32*>((u8*)Yv + off) = pk;
            } else if constexpr (MODE == 1) {
                float4 r0 = *reinterpret_cast<const float4*>(res + off);
                float rr[4] = {r0.x, r0.y, r0.z, r0.w};
                float o[4];
                #pragma unroll
                for (int e = 0; e < 4; ++e)
                    o[e] = acc[t][i][e] * scale[i] + shift[i] + rr[e];
                float4 s0 = {o[0], o[1], o[2], o[3]};
                *reinterpret_cast<float4*>((float*)Yv + off) = s0;
            } else {
                float* op = (float*)Yv + off;
                float4 r0 = *reinterpret_cast<const float4*>(op);
                float rr[4] = {r0.x, r0.y, r0.z, r0.w};
                float o[4];
                #pragma unroll
                for (int e = 0; e < 4; ++e) {
                    const float y = acc[t][i][e] * scale[i] + shift[i];
                    v[e] += (y - v[e]) * 0.5f;
                    const u32 s = (v[e] >= 0.5f) ? 1u : 0u;
                    v[e] = s ? 0.0f : v[e];
                    o[e] = rr[e] + (s ? 1.0f : 0.0f);
                }
                float4 s0 = {o[0], o[1], o[2], o[3]};
                *reinterpret_cast<float4*>(op) = s0;
            }
        }
    }
}

// ---------------------------------------------------------------------------
// kv_raw[row=tb*C+c] = sum_n k*v  (exact integer; round-2 verbatim)
// ---------------------------------------------------------------------------
__global__ __launch_bounds__(256) void kv_reduce(const u8* __restrict__ ks,
                                                 const u8* __restrict__ vs,
                                                 float* __restrict__ kv)
{
    const int row = blockIdx.x * 4 + (threadIdx.x >> 6);  // [0, T*B*C)
    const int lane = threadIdx.x & 63;
    const u8* kp = ks + (size_t)row * N_SP;
    const u8* vp = vs + (size_t)row * N_SP;
    int acc = 0;
    #pragma unroll
    for (int n = 0; n < N_SP; n += 256) {
        uchar4 a = *reinterpret_cast<const uchar4*>(kp + n + lane * 4);
        uchar4 c = *reinterpret_cast<const uchar4*>(vp + n + lane * 4);
        acc += (a.x & c.x) + (a.y & c.y) + (a.z & c.z) + (a.w & c.w);
    }
    #pragma unroll
    for (int off = 32; off; off >>= 1) acc += __shfl_down(acc, off, 64);
    if (lane == 0) kv[row] = (float)acc;
}

// ---------------------------------------------------------------------------
// talking heads (8x8 over heads) + LIF -> kvs float {0,1}  (round-2 verbatim)
// ---------------------------------------------------------------------------
__global__ __launch_bounds__(256) void th_lif(const float* __restrict__ kvraw,
                                              const float* __restrict__ th,
                                              float* __restrict__ kvs)
{
    const int i = blockIdx.x * 256 + threadIdx.x;   // [0, B*C)
    const int b = i >> 9;
    const int c = i & 511;
    const int g = c >> 6;
    const int dd = c & 63;
    float v = 0.0f;
    #pragma unroll
    for (int t = 0; t < T_STEPS; ++t) {
        const float* base = kvraw + ((size_t)t * B_SZ + b) * C_IN;
        float x = 0.0f;
        #pragma unroll
        for (int hh = 0; hh < 8; ++hh)
            x += base[hh * 64 + dd] * th[g * 8 + hh];
        v += (x - v) * 0.5f;
        const float s = (v >= 0.5f) ? 1.0f : 0.0f;
        kvs[((size_t)t * B_SZ + b) * C_IN + c] = s;
        v = (s != 0.0f) ? 0.0f : v;
    }
}

extern "C" void kernel_launch(void* const* d_in, const int* in_sizes, int n_in,
                              void* d_out, int out_size, void* d_ws, size_t ws_size,
                              hipStream_t stream)
{
    const float* x       = (const float*)d_in[0];
    const float* q_w     = (const float*)d_in[1];
    const float* q_bn    = (const float*)d_in[2];
    const float* k_w     = (const float*)d_in[3];
    const float* k_bn    = (const float*)d_in[4];
    const float* v_w     = (const float*)d_in[5];
    const float* v_bn    = (const float*)d_in[6];
    const float* th_w    = (const float*)d_in[7];
    const float* proj_w  = (const float*)d_in[8];
    const float* proj_b  = (const float*)d_in[9];
    const float* proj_bn = (const float*)d_in[10];
    const float* fc1_w   = (const float*)d_in[11];
    const float* fc1_b   = (const float*)d_in[12];
    const float* fc1_bn  = (const float*)d_in[13];
    const float* fc2_w   = (const float*)d_in[14];
    const float* fc2_b   = (const float*)d_in[15];
    const float* fc2_bn  = (const float*)d_in[16];
    float* out = (float*)d_out;

    // workspace: round-2/6/9's proven 64 MiB + 128 KiB map
    u8* ws = (u8*)d_ws;
    const size_t SLOT = (size_t)T_STEPS * S_C;        // 16 MiB per u8 slot
    u8* xs = ws;                    // [TB][C][N] u8
    u8* qs = ws + SLOT;
    u8* ks = ws + 2 * SLOT;
    u8* vs = ws + 3 * SLOT;
    float* kvraw = (float*)(ws + 4 * SLOT);                 // [TB][C] f32 (64 KiB)
    float* kvsf  = kvraw + (size_t)T_STEPS * B_SZ * C_IN;   // [TB][C] f32 (64 KiB)
    u8* hdn = ws;                   // [TB][Ch][N] u8 = 64 MiB, reuses xs..vs (dead by fc1)

    // 1. xs = lif(x)
    lif_x_kernel<<<(int)(S_C / 256), 256, 0, stream>>>(x, xs);

    // 2. q/k/v = lif(bn(conv(xs)))  — fused triple GEMM, t-folded
    //    grid = 16 n * 8 co * 3 sel * 8 b = 3072
    mm<0, 0, false, 512, 512, 3><<<3072, 256, 0, stream>>>(
        q_w, k_w, v_w, xs, q_bn, k_bn, v_bn, nullptr, nullptr, nullptr, qs, ks, vs);

    // 3. kv_raw = rowwise dot(k, v); 4. talking heads + lif -> kvs (float 0/1)
    kv_reduce<<<(T_STEPS * B_SZ * C_IN) / 4, 256, 0, stream>>>(ks, vs, kvraw);
    th_lif<<<(B_SZ * C_IN) / 256, 256, 0, stream>>>(kvraw, th_w, kvsf);

    // 5. xout = bn(proj(q * kvs) + b) + x  -> d_out;  grid 16*8*8 = 1024
    mm<1, 1, true, 512, 512, 1><<<1024, 256, 0, stream>>>(
        proj_w, nullptr, nullptr, qs, proj_bn, nullptr, nullptr, proj_b, kvsf, x,
        out, nullptr, nullptr);

    // 6. hdn = lif(bn(fc1(xout) + b));  grid 16*32*8 = 4096
    mm<0, 2, true, 512, 2048, 1><<<4096, 256, 0, stream>>>(
        fc1_w, nullptr, nullptr, out, fc1_bn, nullptr, nullptr, fc1_b, nullptr, nullptr,
        hdn, nullptr, nullptr);

    // 7. out = lif(bn(fc2(hdn) + b)) + xout  (in place on d_out);  grid 1024
    mm<2, 0, true, 2048, 512, 1><<<1024, 256, 0, stream>>>(
        fc2_w, nullptr, nullptr, hdn, fc2_bn, nullptr, nullptr, fc2_b, nullptr, nullptr,
        out, nullptr, nullptr);
}